// Round 5
// baseline (556.005 us; speedup 1.0000x reference)
//
#include <hip/hip_runtime.h>

// DIMKT: B=1024, S=200, D=128.
// R5: R4 structure (MFMA y-dot via SS - sum(x*s), no shuffles/DotBuf; MFMA
// projection) with RNE bf16 stores everywhere -- truncation's toward-zero
// bias times the large Sigma(x*s) magnitude was R4's 5.5e-2 failure.
// Scan: 64 blocks x 512 thr (8 waves x 16 cols), distance-2 static prefetch,
// lgkm-only barriers.

#define S_LEN 200
#define NBATCH 1024
#define DIM 128
#define LOG2E 1.4426950408889634f

typedef short short8 __attribute__((ext_vector_type(8)));
typedef float f32x4 __attribute__((ext_vector_type(4)));

__device__ __forceinline__ unsigned short f2b(float f) {
  union { float f; unsigned u; } v; v.f = f;
  unsigned r = (v.u + 0x7FFFu + ((v.u >> 16) & 1u)) >> 16;  // RNE
  return (unsigned short)r;
}
__device__ __forceinline__ float b2f(unsigned short b) {
  union { unsigned u; float f; } v; v.u = ((unsigned)b) << 16;
  return v.f;
}
__device__ __forceinline__ float fast_sigmoid(float x) {
  return __builtin_amdgcn_rcpf(1.0f + __builtin_amdgcn_exp2f(-LOG2E * x));
}
__device__ __forceinline__ float fast_tanh(float x) {
  return 2.0f * __builtin_amdgcn_rcpf(1.0f + __builtin_amdgcn_exp2f(-2.0f * LOG2E * x)) - 1.0f;
}
// LDS-only barrier: does NOT drain vmcnt, so global prefetches stay in flight.
__device__ __forceinline__ void wg_barrier_lds() {
  __asm__ volatile("s_waitcnt lgkmcnt(0)\n\ts_barrier" ::: "memory");
}

// ---------------- P1: projected embedding tables via MFMA.
// T[r][n] = sum_k E[r][k] * W[n][coff+k].  16 rows/block, 4 waves x 32 cols.
// blocks: [0,3125) Tq | [3125,3188) Tc | [3188,3195) Tqd | [3195,3202) Tcd |
// [3202,3304) small tables.
__global__ void proj_all_kernel(const float* __restrict__ Eq, const float* __restrict__ Ec,
                                const float* __restrict__ Eqd, const float* __restrict__ Ecd,
                                const float* __restrict__ Ecorr,
                                const float* __restrict__ Wx,
                                const float* __restrict__ Wp1, const float* __restrict__ bp1,
                                const float* __restrict__ Wp2, const float* __restrict__ bp2,
                                const float* __restrict__ Wk, const float* __restrict__ bk,
                                unsigned short* __restrict__ Tq, unsigned short* __restrict__ Tc,
                                unsigned short* __restrict__ Tqd, unsigned short* __restrict__ Tcd,
                                unsigned short* __restrict__ Tkqd, unsigned short* __restrict__ Tkcd,
                                float* __restrict__ Tkc, float* __restrict__ Tp1c,
                                float* __restrict__ Tp2c) {
  const int bid = blockIdx.x;
  const int tid = threadIdx.x;
  if (bid >= 3202) {
    const int blk = bid - 3202;
    if (blk < 101) {
      const int o = tid & 127, half = tid >> 7;
      const float* e = (half ? Ecd : Eqd) + (size_t)blk * DIM;
      const float* wr = Wk + (size_t)o * 512 + (half ? 384 : 256);
      float a = 0.f;
      for (int k = 0; k < DIM; ++k) a = fmaf(e[k], wr[k], a);
      (half ? Tkcd : Tkqd)[blk * DIM + o] = f2b(a);
    } else {
      for (int idx = tid; idx < 768; idx += 256) {
        const int t = idx >> 8, e = (idx >> 7) & 1, o = idx & 127;
        const float* ec = Ecorr + e * DIM;
        const float* wr; float bias; float* dst;
        if (t == 0)      { wr = Wp1 + (size_t)o * 256 + 128; bias = bp1[o]; dst = Tp1c; }
        else if (t == 1) { wr = Wp2 + (size_t)o * 256 + 128; bias = bp2[o]; dst = Tp2c; }
        else             { wr = Wk  + (size_t)o * 512 + 128; bias = bk[o];  dst = Tkc;  }
        float a = bias;
        for (int k = 0; k < DIM; ++k) a = fmaf(ec[k], wr[k], a);
        dst[e * DIM + o] = a;
      }
    }
    return;
  }
  const float* E; int M, coff, r0; unsigned short* T;
  if (bid < 3125)      { E = Eq;  M = 50000; coff = 0;   T = Tq;  r0 = bid * 16; }
  else if (bid < 3188) { E = Ec;  M = 1000;  coff = 128; T = Tc;  r0 = (bid - 3125) * 16; }
  else if (bid < 3195) { E = Eqd; M = 101;   coff = 256; T = Tqd; r0 = (bid - 3188) * 16; }
  else                 { E = Ecd; M = 101;   coff = 384; T = Tcd; r0 = (bid - 3195) * 16; }

  __shared__ __align__(16) unsigned short A[16][136];
  {
    const int row = tid >> 4, c8 = (tid & 15) * 8;
    union U8 { uint4 v; unsigned short s[8]; } o;
    if (r0 + row < M) {
      const float4 e0 = *(const float4*)(E + (size_t)(r0 + row) * DIM + c8);
      const float4 e1 = *(const float4*)(E + (size_t)(r0 + row) * DIM + c8 + 4);
      o.s[0] = f2b(e0.x); o.s[1] = f2b(e0.y); o.s[2] = f2b(e0.z); o.s[3] = f2b(e0.w);
      o.s[4] = f2b(e1.x); o.s[5] = f2b(e1.y); o.s[6] = f2b(e1.z); o.s[7] = f2b(e1.w);
    } else {
      o.v = make_uint4(0, 0, 0, 0);
    }
    *(uint4*)&A[row][c8] = o.v;
  }
  __syncthreads();
  const int w = tid >> 6, L = tid & 63, q = L >> 4, m = L & 15;
  // B-frags: n = 32w+16T+m, k = kb*32+q*8+j
  short8 bf[2][4];
#pragma unroll
  for (int T2 = 0; T2 < 2; ++T2) {
    const int n = 32 * w + 16 * T2 + m;
#pragma unroll
    for (int kb = 0; kb < 4; ++kb) {
      const float* src = Wx + (size_t)n * 512 + coff + kb * 32 + q * 8;
      const float4 v0 = *(const float4*)src;
      const float4 v1 = *(const float4*)(src + 4);
      short8 f;
      f[0] = (short)f2b(v0.x); f[1] = (short)f2b(v0.y);
      f[2] = (short)f2b(v0.z); f[3] = (short)f2b(v0.w);
      f[4] = (short)f2b(v1.x); f[5] = (short)f2b(v1.y);
      f[6] = (short)f2b(v1.z); f[7] = (short)f2b(v1.w);
      bf[T2][kb] = f;
    }
  }
  short8 af[4];
#pragma unroll
  for (int kb = 0; kb < 4; ++kb) af[kb] = *(const short8*)&A[m][kb * 32 + q * 8];
  const f32x4 vzero = {0.f, 0.f, 0.f, 0.f};
  f32x4 acc[2] = {vzero, vzero};
#pragma unroll
  for (int kb = 0; kb < 4; ++kb) {
#pragma unroll
    for (int T2 = 0; T2 < 2; ++T2)
      acc[T2] = __builtin_amdgcn_mfma_f32_16x16x32_bf16(af[kb], bf[T2][kb], acc[T2], 0, 0, 0);
  }
#pragma unroll
  for (int T2 = 0; T2 < 2; ++T2) {
    const int col = 32 * w + 16 * T2 + m;
#pragma unroll
    for (int i = 0; i < 4; ++i) {
      const int r = r0 + q * 4 + i;
      if (r < M) T[(size_t)r * DIM + col] = f2b(acc[T2][i]);
    }
  }
}

// ---------------- P2: x[s][b][:] = Tq+Tc+Tqd+Tcd+bx (bf16) and SS[s][b]=sum(x^2)
__global__ void build_x_kernel(const int* __restrict__ qs, const int* __restrict__ cs,
                               const int* __restrict__ qds, const int* __restrict__ cds,
                               const unsigned short* __restrict__ Tq, const unsigned short* __restrict__ Tc,
                               const unsigned short* __restrict__ Tqd, const unsigned short* __restrict__ Tcd,
                               const float* __restrict__ bx, unsigned short* __restrict__ xg,
                               float* __restrict__ SSg) {
  const int r = blockIdx.x * 16 + (threadIdx.x >> 4);   // r = s*1024 + b
  const int c8 = (threadIdx.x & 15) * 8;
  const int s = r >> 10, b = r & 1023;
  const int q = qs[b * S_LEN + s], c = cs[b * S_LEN + s];
  const int qd = qds[b * S_LEN + s], cd = cds[b * S_LEN + s];
  union U8 { uint4 v; unsigned short s[8]; };
  U8 vq, vc, vd, ve, o;
  vq.v = *(const uint4*)(Tq + (size_t)q * DIM + c8);
  vc.v = *(const uint4*)(Tc + (size_t)c * DIM + c8);
  vd.v = *(const uint4*)(Tqd + (size_t)qd * DIM + c8);
  ve.v = *(const uint4*)(Tcd + (size_t)cd * DIM + c8);
  const float4 bx0 = *(const float4*)(bx + c8);
  const float4 bx1 = *(const float4*)(bx + c8 + 4);
  float bb[8] = {bx0.x, bx0.y, bx0.z, bx0.w, bx1.x, bx1.y, bx1.z, bx1.w};
  float part = 0.f;
#pragma unroll
  for (int j = 0; j < 8; ++j) {
    const float sv = b2f(vq.s[j]) + b2f(vc.s[j]) + b2f(vd.s[j]) + b2f(ve.s[j]) + bb[j];
    o.s[j] = f2b(sv);
    const float xr = b2f(o.s[j]);   // match bf16 value the scan will read
    part = fmaf(xr, xr, part);
  }
  *(uint4*)(xg + (size_t)r * DIM + c8) = o.v;
#pragma unroll
  for (int off = 1; off <= 8; off <<= 1) part += __shfl_xor(part, off, 64);
  if ((threadIdx.x & 15) == 0) SSg[r] = part;
}

// ---------------- P2b: GG[r][n] = (x[r] @ Wk[:, :128].T)[n]  (bf16), r = t*1024+b
__global__ void gemm_xwk_kernel(const unsigned short* __restrict__ xg,
                                const float* __restrict__ Wk,
                                unsigned short* __restrict__ GG) {
  const int tid = threadIdx.x;
  const int w = tid >> 6, L = tid & 63, q = L >> 4, m = L & 15;
  const int rbase = blockIdx.x * 64;
  short8 wk[2][4];
#pragma unroll
  for (int T = 0; T < 2; ++T) {
    const int n = 32 * w + 16 * T + m;
#pragma unroll
    for (int kb = 0; kb < 4; ++kb) {
      const float* src = Wk + (size_t)n * 512 + kb * 32 + q * 8;
      const float4 v0 = *(const float4*)src;
      const float4 v1 = *(const float4*)(src + 4);
      short8 f;
      f[0] = (short)f2b(v0.x); f[1] = (short)f2b(v0.y);
      f[2] = (short)f2b(v0.z); f[3] = (short)f2b(v0.w);
      f[4] = (short)f2b(v1.x); f[5] = (short)f2b(v1.y);
      f[6] = (short)f2b(v1.z); f[7] = (short)f2b(v1.w);
      wk[T][kb] = f;
    }
  }
  const f32x4 vzero = {0.f, 0.f, 0.f, 0.f};
#pragma unroll
  for (int mt = 0; mt < 4; ++mt) {
    short8 af[4];
#pragma unroll
    for (int kb = 0; kb < 4; ++kb)
      af[kb] = *(const short8*)(xg + (size_t)(rbase + mt * 16 + m) * DIM + kb * 32 + q * 8);
    f32x4 acc[2] = {vzero, vzero};
#pragma unroll
    for (int kb = 0; kb < 4; ++kb) {
#pragma unroll
      for (int T = 0; T < 2; ++T)
        acc[T] = __builtin_amdgcn_mfma_f32_16x16x32_bf16(af[kb], wk[T][kb], acc[T], 0, 0, 0);
    }
#pragma unroll
    for (int T = 0; T < 2; ++T) {
      const int col = 32 * w + 16 * T + m;
#pragma unroll
      for (int i = 0; i < 4; ++i)
        GG[(size_t)(rbase + mt * 16 + q * 4 + i) * DIM + col] = f2b(acc[T][i]);
    }
  }
}

// ---------------- P2c: GG[t][b][:] += Tkc[corr](incl bk) + Tkqd[qd] + Tkcd[cd]
__global__ void build_gpre_add_kernel(const int* __restrict__ corr, const int* __restrict__ qds,
                                      const int* __restrict__ cds,
                                      const float* __restrict__ Tkc,
                                      const unsigned short* __restrict__ Tkqd,
                                      const unsigned short* __restrict__ Tkcd,
                                      unsigned short* __restrict__ gg) {
  const int r = blockIdx.x * 16 + (threadIdx.x >> 4);   // r = t*1024 + b, t<=198
  const int c8 = (threadIdx.x & 15) * 8;
  const int t = r >> 10, b = r & 1023;
  const int ci = corr[b * S_LEN + t], qi = qds[b * S_LEN + t], di = cds[b * S_LEN + t];
  union U8 { uint4 v; unsigned short s[8]; };
  U8 vq, vc, vg, o;
  vg.v = *(const uint4*)(gg + (size_t)r * DIM + c8);
  vq.v = *(const uint4*)(Tkqd + (size_t)qi * DIM + c8);
  vc.v = *(const uint4*)(Tkcd + (size_t)di * DIM + c8);
  const float4 k0 = *(const float4*)(Tkc + (size_t)ci * DIM + c8);
  const float4 k1 = *(const float4*)(Tkc + (size_t)ci * DIM + c8 + 4);
  float kk[8] = {k0.x, k0.y, k0.z, k0.w, k1.x, k1.y, k1.z, k1.w};
#pragma unroll
  for (int j = 0; j < 8; ++j)
    o.s[j] = f2b(b2f(vg.s[j]) + kk[j] + b2f(vq.s[j]) + b2f(vc.s[j]));
  *(uint4*)(gg + (size_t)r * DIM + c8) = o.v;
}

// ---------------- P3: the recurrence. 64 blocks x 512 thr (8 waves x 16 cols).
__global__ __launch_bounds__(512, 2) void scan_kernel(
    const unsigned short* __restrict__ xg,    // [S][B][D] bf16
    const unsigned short* __restrict__ gg,    // [S-1][B][D] bf16 (xWk + tables + bk)
    const float* __restrict__ SSg,            // [S][B] fp32, sum(x^2)
    const float* __restrict__ h0,
    const float* __restrict__ Ws1, const float* __restrict__ bs1,
    const float* __restrict__ Ws2, const float* __restrict__ bs2,
    const float* __restrict__ Wp1, const float* __restrict__ Wp2,
    const float* __restrict__ Wk,
    const float* __restrict__ gTp1c, const float* __restrict__ gTp2c,
    const int* __restrict__ corr_seq,
    float* __restrict__ outp) {
  __shared__ __align__(16) unsigned short Sbuf[16][136];  // s_in (bf16)
  __shared__ __align__(16) unsigned short Pbuf[16][136];  // sdf (bf16)

  const int tid = threadIdx.x;
  const int w = tid >> 6, L = tid & 63, q = L >> 4, m = L & 15;
  const int col16 = 16 * w + m;
  const int rbase = blockIdx.x << 4;

  short8 wf[5][4];
  {
    const float* Wptr[5] = {Ws1, Ws2, Wp1, Wp2, Wk};
    const int ldw[5] = {128, 128, 256, 256, 512};
#pragma unroll
    for (int M = 0; M < 5; ++M) {
#pragma unroll
      for (int kb = 0; kb < 4; ++kb) {
        const float* src = Wptr[M] + (size_t)col16 * ldw[M] + kb * 32 + q * 8;
        const float4 v0 = *(const float4*)src;
        const float4 v1 = *(const float4*)(src + 4);
        short8 f;
        f[0] = (short)f2b(v0.x); f[1] = (short)f2b(v0.y);
        f[2] = (short)f2b(v0.z); f[3] = (short)f2b(v0.w);
        f[4] = (short)f2b(v1.x); f[5] = (short)f2b(v1.y);
        f[6] = (short)f2b(v1.z); f[7] = (short)f2b(v1.w);
        wf[M][kb] = f;
      }
    }
  }
  const float bs1v = bs1[col16], bs2v = bs2[col16];
  const float tp1v0 = gTp1c[col16], tp1v1 = gTp1c[DIM + col16];
  const float tp2v0 = gTp2c[col16], tp2v1 = gTp2c[DIM + col16];

  float h[4];
#pragma unroll
  for (int i = 0; i < 4; ++i) {
    const int b = rbase + q * 4 + i;
    const float hv = h0[(size_t)b * DIM + col16];
    h[i] = hv;
    const float xt = b2f(xg[(size_t)b * DIM + col16]);  // s=0
    Sbuf[q * 4 + i][col16] = f2b(xt - hv);
  }
  if (tid < 16) outp[(size_t)(rbase + tid) * S_LEN + (S_LEN - 1)] = 0.0f;

  // distance-2 prefetch sets (STATIC indexing only)
  unsigned short xpA[4], ggA[4], xpB[4], ggB[4];
  int cpA[4], cpB[4];
  short8 xfA[4], xfB[4];
  float ssA, ssB;
#pragma unroll
  for (int i = 0; i < 4; ++i) {
    const int b = rbase + q * 4 + i;
    xpA[i] = xg[((size_t)1 * NBATCH + b) * DIM + col16];
    ggA[i] = gg[((size_t)0 * NBATCH + b) * DIM + col16];
    cpA[i] = corr_seq[b * S_LEN + 0];
    xpB[i] = xg[((size_t)2 * NBATCH + b) * DIM + col16];
    ggB[i] = gg[((size_t)1 * NBATCH + b) * DIM + col16];
    cpB[i] = corr_seq[b * S_LEN + 1];
  }
#pragma unroll
  for (int kb = 0; kb < 4; ++kb) {
    xfA[kb] = *(const short8*)(xg + ((size_t)0 * NBATCH + rbase + m) * DIM + kb * 32 + q * 8);
    xfB[kb] = *(const short8*)(xg + ((size_t)1 * NBATCH + rbase + m) * DIM + kb * 32 + q * 8);
  }
  ssA = SSg[(size_t)0 * NBATCH + rbase + m];
  ssB = SSg[(size_t)1 * NBATCH + rbase + m];

  const f32x4 vzero = {0.f, 0.f, 0.f, 0.f};

#define STEP(TCUR, XP, GP, CP, XF, SSP)                                        \
  do {                                                                         \
    const int t_ = (TCUR);                                                     \
    float xnv[4], ggv[4];                                                      \
    int cin[4];                                                                \
    short8 xfr[4];                                                             \
    float ssv = SSP;                                                           \
    _Pragma("unroll") for (int i = 0; i < 4; ++i) {                            \
      xnv[i] = b2f(XP[i]);                                                     \
      ggv[i] = b2f(GP[i]);                                                     \
      cin[i] = CP[i];                                                          \
    }                                                                          \
    _Pragma("unroll") for (int kb = 0; kb < 4; ++kb) xfr[kb] = XF[kb];         \
    {                                                                          \
      const int tp_ = (t_ + 2 <= 198) ? t_ + 2 : 198;                          \
      _Pragma("unroll") for (int i = 0; i < 4; ++i) {                          \
        const int b = rbase + q * 4 + i;                                       \
        XP[i] = xg[((size_t)(tp_ + 1) * NBATCH + b) * DIM + col16];            \
        GP[i] = gg[((size_t)tp_ * NBATCH + b) * DIM + col16];                  \
        CP[i] = corr_seq[b * S_LEN + tp_];                                     \
      }                                                                        \
      _Pragma("unroll") for (int kb = 0; kb < 4; ++kb)                         \
        XF[kb] = *(const short8*)(xg + ((size_t)tp_ * NBATCH + rbase + m) * DIM + kb * 32 + q * 8); \
      SSP = SSg[(size_t)tp_ * NBATCH + rbase + m];                             \
    }                                                                          \
    wg_barrier_lds(); /* Sbuf(t) ready */                                      \
    short8 sf[4];                                                              \
    _Pragma("unroll") for (int kb = 0; kb < 4; ++kb)                           \
        sf[kb] = *(const short8*)&Sbuf[m][kb * 32 + q * 8];                    \
    f32x4 a1 = vzero, a2 = vzero, c1 = vzero, dt = vzero;                      \
    _Pragma("unroll") for (int kb = 0; kb < 4; ++kb) {                         \
      a1 = __builtin_amdgcn_mfma_f32_16x16x32_bf16(sf[kb], wf[0][kb], a1, 0, 0, 0); \
      a2 = __builtin_amdgcn_mfma_f32_16x16x32_bf16(sf[kb], wf[1][kb], a2, 0, 0, 0); \
      c1 = __builtin_amdgcn_mfma_f32_16x16x32_bf16(sf[kb], wf[4][kb], c1, 0, 0, 0); \
      dt = __builtin_amdgcn_mfma_f32_16x16x32_bf16(sf[kb], xfr[kb], dt, 0, 0, 0);   \
    }                                                                          \
    if (t_ > 0 && w == 0 && q == (m >> 2)) {                                   \
      const int ii = m & 3;                                                    \
      const float D = ii == 0 ? dt[0] : ii == 1 ? dt[1] : ii == 2 ? dt[2] : dt[3]; \
      outp[(size_t)(rbase + m) * S_LEN + (t_ - 1)] = fast_sigmoid(ssv - D);    \
    }                                                                          \
    _Pragma("unroll") for (int i = 0; i < 4; ++i) {                            \
      const float sg = fast_sigmoid(a1[i] + bs1v);                             \
      const float th = fast_tanh(a2[i] + bs2v);                                \
      Pbuf[q * 4 + i][col16] = f2b(sg * th);                                   \
    }                                                                          \
    wg_barrier_lds(); /* Pbuf ready */                                         \
    short8 pf[4];                                                              \
    _Pragma("unroll") for (int kb = 0; kb < 4; ++kb)                           \
        pf[kb] = *(const short8*)&Pbuf[m][kb * 32 + q * 8];                    \
    f32x4 p1 = vzero, p2 = vzero;                                              \
    _Pragma("unroll") for (int kb = 0; kb < 4; ++kb) {                         \
      p1 = __builtin_amdgcn_mfma_f32_16x16x32_bf16(pf[kb], wf[2][kb], p1, 0, 0, 0); \
      p2 = __builtin_amdgcn_mfma_f32_16x16x32_bf16(pf[kb], wf[3][kb], p2, 0, 0, 0); \
    }                                                                          \
    _Pragma("unroll") for (int i = 0; i < 4; ++i) {                            \
      const float g = fast_sigmoid(ggv[i] - c1[i]);                            \
      const float t1 = cin[i] ? tp1v1 : tp1v0;                                 \
      const float t2 = cin[i] ? tp2v1 : tp2v0;                                 \
      const float pka = fast_sigmoid(p1[i] + t1) * fast_tanh(p2[i] + t2);      \
      const float hn = pka + g * (h[i] - pka);                                 \
      h[i] = hn;                                                               \
      Sbuf[q * 4 + i][col16] = f2b(xnv[i] - hn);                               \
    }                                                                          \
  } while (0)

  for (int t2 = 0; t2 < 198; t2 += 2) {
    STEP(t2, xpA, ggA, cpA, xfA, ssA);
    STEP(t2 + 1, xpB, ggB, cpB, xfB, ssB);
  }
  STEP(198, xpA, ggA, cpA, xfA, ssA);
#undef STEP

  // epilogue: y(198) from s(199) in Sbuf and x(199)
  wg_barrier_lds();
  {
    short8 sf[4], xf9[4];
#pragma unroll
    for (int kb = 0; kb < 4; ++kb) {
      sf[kb] = *(const short8*)&Sbuf[m][kb * 32 + q * 8];
      xf9[kb] = *(const short8*)(xg + ((size_t)199 * NBATCH + rbase + m) * DIM + kb * 32 + q * 8);
    }
    f32x4 dt = vzero;
#pragma unroll
    for (int kb = 0; kb < 4; ++kb)
      dt = __builtin_amdgcn_mfma_f32_16x16x32_bf16(sf[kb], xf9[kb], dt, 0, 0, 0);
    const float ssv = SSg[(size_t)199 * NBATCH + rbase + m];
    if (w == 0 && q == (m >> 2)) {
      const int ii = m & 3;
      const float D = ii == 0 ? dt[0] : ii == 1 ? dt[1] : ii == 2 ? dt[2] : dt[3];
      outp[(size_t)(rbase + m) * S_LEN + (S_LEN - 2)] = fast_sigmoid(ssv - D);
    }
  }
}

extern "C" void kernel_launch(void* const* d_in, const int* in_sizes, int n_in,
                              void* d_out, int out_size, void* d_ws, size_t ws_size,
                              hipStream_t stream) {
  const int* qs    = (const int*)d_in[0];
  const int* cs    = (const int*)d_in[1];
  const int* qds   = (const int*)d_in[2];
  const int* cds   = (const int*)d_in[3];
  const int* corr  = (const int*)d_in[4];
  const float* Eq    = (const float*)d_in[5];
  const float* Ec    = (const float*)d_in[6];
  const float* Eqd   = (const float*)d_in[7];
  const float* Ecd   = (const float*)d_in[8];
  const float* Ecorr = (const float*)d_in[9];
  const float* Wx  = (const float*)d_in[10];
  const float* bx  = (const float*)d_in[11];
  const float* Ws1 = (const float*)d_in[12];
  const float* bs1 = (const float*)d_in[13];
  const float* Ws2 = (const float*)d_in[14];
  const float* bs2 = (const float*)d_in[15];
  const float* Wp1 = (const float*)d_in[16];
  const float* bp1 = (const float*)d_in[17];
  const float* Wp2 = (const float*)d_in[18];
  const float* bp2 = (const float*)d_in[19];
  const float* Wk  = (const float*)d_in[20];
  const float* bk  = (const float*)d_in[21];
  const float* h0  = (const float*)d_in[22];

  char* ws = (char*)d_ws;
  const size_t xbytes = (size_t)S_LEN * NBATCH * DIM * 2;
  const size_t A = (xbytes + 255) & ~(size_t)255;
  const size_t ggbytes = (size_t)(S_LEN - 1) * NBATCH * DIM * 2;
  unsigned short* X  = (unsigned short*)ws;
  unsigned short* GG = (unsigned short*)(ws + A);
  unsigned short* Tq  = GG;  // alias (build phase only)
  unsigned short* Tc  = (unsigned short*)(ws + A + (size_t)50000 * DIM * 2);
  unsigned short* Tqd = (unsigned short*)(ws + A + (size_t)51000 * DIM * 2);
  unsigned short* Tcd = (unsigned short*)(ws + A + (size_t)51101 * DIM * 2);
  size_t off = A + ((ggbytes + 255) & ~(size_t)255);
  auto alloc = [&](size_t bytes) {
    void* p = ws + off;
    off = (off + bytes + 255) & ~(size_t)255;
    return p;
  };
  unsigned short* Tkqd = (unsigned short*)alloc((size_t)101 * DIM * 2);
  unsigned short* Tkcd = (unsigned short*)alloc((size_t)101 * DIM * 2);
  float* Tkc  = (float*)alloc((size_t)2 * DIM * 4);
  float* Tp1c = (float*)alloc((size_t)2 * DIM * 4);
  float* Tp2c = (float*)alloc((size_t)2 * DIM * 4);
  float* SS   = (float*)alloc((size_t)S_LEN * NBATCH * 4);

  proj_all_kernel<<<3304, 256, 0, stream>>>(Eq, Ec, Eqd, Ecd, Ecorr, Wx,
                                            Wp1, bp1, Wp2, bp2, Wk, bk,
                                            Tq, Tc, Tqd, Tcd, Tkqd, Tkcd, Tkc, Tp1c, Tp2c);
  build_x_kernel<<<(S_LEN * NBATCH) / 16, 256, 0, stream>>>(qs, cs, qds, cds, Tq, Tc, Tqd, Tcd,
                                                            bx, X, SS);
  // Tq..Tcd dead now -> GG overwrites them
  gemm_xwk_kernel<<<((S_LEN - 1) * NBATCH) / 64, 256, 0, stream>>>(X, Wk, GG);
  build_gpre_add_kernel<<<((S_LEN - 1) * NBATCH) / 16, 256, 0, stream>>>(corr, qds, cds, Tkc, Tkqd, Tkcd, GG);
  scan_kernel<<<64, 512, 0, stream>>>(X, GG, SS, h0, Ws1, bs1, Ws2, bs2, Wp1, Wp2, Wk,
                                      Tp1c, Tp2c, corr, (float*)d_out);
}

// Round 6
// 513.708 us; speedup vs baseline: 1.0823x; 1.0823x over previous
//
#include <hip/hip_runtime.h>
#include <hip/hip_bf16.h>

// DIMKT: B=1024, S=200, D=128.
// R6: scan VALU-issue diet: pointer-increment prefetch streams (imm-offset
// loads), wave0-only y-dot (was 8x redundant), packed bf16 converts, corr as
// prebuilt float stream. Prep: fused gemm_xwk+gpre (one pass), 64-row proj.

#define S_LEN 200
#define NBATCH 1024
#define DIM 128
#define LOG2E 1.4426950408889634f

typedef short short8 __attribute__((ext_vector_type(8)));
typedef float f32x4 __attribute__((ext_vector_type(4)));

__device__ __forceinline__ unsigned short f2b(float f) {
  union { float f; unsigned u; } v; v.f = f;
  unsigned r = (v.u + 0x7FFFu + ((v.u >> 16) & 1u)) >> 16;  // RNE
  return (unsigned short)r;
}
__device__ __forceinline__ float b2f(unsigned short b) {
  union { unsigned u; float f; } v; v.u = ((unsigned)b) << 16;
  return v.f;
}
// packed RNE f32x2 -> bf16x2 (v_cvt_pk_bf16_f32 on gfx950; header fallback else)
__device__ __forceinline__ unsigned pk_bf16(float lo, float hi) {
  __hip_bfloat162 t = __float22bfloat162_rn(make_float2(lo, hi));
  union { __hip_bfloat162 h; unsigned u; } cv; cv.h = t;
  return cv.u;
}
__device__ __forceinline__ float fast_sigmoid(float x) {
  return __builtin_amdgcn_rcpf(1.0f + __builtin_amdgcn_exp2f(-LOG2E * x));
}
__device__ __forceinline__ float fast_tanh(float x) {
  return 2.0f * __builtin_amdgcn_rcpf(1.0f + __builtin_amdgcn_exp2f(-2.0f * LOG2E * x)) - 1.0f;
}
// LDS-only barrier: does NOT drain vmcnt, prefetches stay in flight.
__device__ __forceinline__ void wg_barrier_lds() {
  __asm__ volatile("s_waitcnt lgkmcnt(0)\n\ts_barrier" ::: "memory");
}

// ---------------- P1: projected embedding tables via MFMA, 64 rows/block.
// blocks: [0,782) Tq | [782,798) Tc | [798,800) Tqd | [800,802) Tcd | [802,904) small
__global__ void proj_all_kernel(const float* __restrict__ Eq, const float* __restrict__ Ec,
                                const float* __restrict__ Eqd, const float* __restrict__ Ecd,
                                const float* __restrict__ Ecorr,
                                const float* __restrict__ Wx,
                                const float* __restrict__ Wp1, const float* __restrict__ bp1,
                                const float* __restrict__ Wp2, const float* __restrict__ bp2,
                                const float* __restrict__ Wk, const float* __restrict__ bk,
                                unsigned short* __restrict__ Tq, unsigned short* __restrict__ Tc,
                                unsigned short* __restrict__ Tqd, unsigned short* __restrict__ Tcd,
                                unsigned short* __restrict__ Tkqd, unsigned short* __restrict__ Tkcd,
                                float* __restrict__ Tkc, float* __restrict__ Tp1c,
                                float* __restrict__ Tp2c) {
  const int bid = blockIdx.x;
  const int tid = threadIdx.x;
  if (bid >= 802) {
    const int blk = bid - 802;
    if (blk < 101) {
      const int o = tid & 127, half = tid >> 7;
      const float* e = (half ? Ecd : Eqd) + (size_t)blk * DIM;
      const float* wr = Wk + (size_t)o * 512 + (half ? 384 : 256);
      float a = 0.f;
      for (int k = 0; k < DIM; ++k) a = fmaf(e[k], wr[k], a);
      (half ? Tkcd : Tkqd)[blk * DIM + o] = f2b(a);
    } else {
      for (int idx = tid; idx < 768; idx += 256) {
        const int t = idx >> 8, e = (idx >> 7) & 1, o = idx & 127;
        const float* ec = Ecorr + e * DIM;
        const float* wr; float bias; float* dst;
        if (t == 0)      { wr = Wp1 + (size_t)o * 256 + 128; bias = bp1[o]; dst = Tp1c; }
        else if (t == 1) { wr = Wp2 + (size_t)o * 256 + 128; bias = bp2[o]; dst = Tp2c; }
        else             { wr = Wk  + (size_t)o * 512 + 128; bias = bk[o];  dst = Tkc;  }
        float a = bias;
        for (int k = 0; k < DIM; ++k) a = fmaf(ec[k], wr[k], a);
        dst[e * DIM + o] = a;
      }
    }
    return;
  }
  const float* E; int M, coff, r0; unsigned short* T;
  if (bid < 782)      { E = Eq;  M = 50000; coff = 0;   T = Tq;  r0 = bid * 64; }
  else if (bid < 798) { E = Ec;  M = 1000;  coff = 128; T = Tc;  r0 = (bid - 782) * 64; }
  else if (bid < 800) { E = Eqd; M = 101;   coff = 256; T = Tqd; r0 = (bid - 798) * 64; }
  else                { E = Ecd; M = 101;   coff = 384; T = Tcd; r0 = (bid - 800) * 64; }

  __shared__ __align__(16) unsigned short A[64][136];
  {
    const int row = tid >> 2, cb = (tid & 3) * 32;
    union U8 { uint4 v; unsigned short s[8]; } o;
#pragma unroll
    for (int cc = 0; cc < 4; ++cc) {
      const int c8 = cb + cc * 8;
      if (r0 + row < M) {
        const float4 e0 = *(const float4*)(E + (size_t)(r0 + row) * DIM + c8);
        const float4 e1 = *(const float4*)(E + (size_t)(r0 + row) * DIM + c8 + 4);
        o.s[0] = f2b(e0.x); o.s[1] = f2b(e0.y); o.s[2] = f2b(e0.z); o.s[3] = f2b(e0.w);
        o.s[4] = f2b(e1.x); o.s[5] = f2b(e1.y); o.s[6] = f2b(e1.z); o.s[7] = f2b(e1.w);
      } else {
        o.v = make_uint4(0, 0, 0, 0);
      }
      *(uint4*)&A[row][c8] = o.v;
    }
  }
  __syncthreads();
  const int w = tid >> 6, L = tid & 63, q = L >> 4, m = L & 15;
  short8 bf[2][4];
#pragma unroll
  for (int T2 = 0; T2 < 2; ++T2) {
    const int n = 32 * w + 16 * T2 + m;
#pragma unroll
    for (int kb = 0; kb < 4; ++kb) {
      const float* src = Wx + (size_t)n * 512 + coff + kb * 32 + q * 8;
      const float4 v0 = *(const float4*)src;
      const float4 v1 = *(const float4*)(src + 4);
      short8 f;
      f[0] = (short)f2b(v0.x); f[1] = (short)f2b(v0.y);
      f[2] = (short)f2b(v0.z); f[3] = (short)f2b(v0.w);
      f[4] = (short)f2b(v1.x); f[5] = (short)f2b(v1.y);
      f[6] = (short)f2b(v1.z); f[7] = (short)f2b(v1.w);
      bf[T2][kb] = f;
    }
  }
  const f32x4 vzero = {0.f, 0.f, 0.f, 0.f};
#pragma unroll
  for (int mt = 0; mt < 4; ++mt) {
    short8 af[4];
#pragma unroll
    for (int kb = 0; kb < 4; ++kb) af[kb] = *(const short8*)&A[mt * 16 + m][kb * 32 + q * 8];
    f32x4 acc[2] = {vzero, vzero};
#pragma unroll
    for (int kb = 0; kb < 4; ++kb) {
#pragma unroll
      for (int T2 = 0; T2 < 2; ++T2)
        acc[T2] = __builtin_amdgcn_mfma_f32_16x16x32_bf16(af[kb], bf[T2][kb], acc[T2], 0, 0, 0);
    }
#pragma unroll
    for (int T2 = 0; T2 < 2; ++T2) {
      const int col = 32 * w + 16 * T2 + m;
#pragma unroll
      for (int i = 0; i < 4; ++i) {
        const int r = r0 + mt * 16 + q * 4 + i;
        if (r < M) T[(size_t)r * DIM + col] = f2b(acc[T2][i]);
      }
    }
  }
}

// ---------------- P2: x[s][b][:] = Tq+Tc+Tqd+Tcd+bx (bf16), SS[s][b]=sum(x^2),
// corrf[s][b] = (float)correct
__global__ void build_x_kernel(const int* __restrict__ qs, const int* __restrict__ cs,
                               const int* __restrict__ qds, const int* __restrict__ cds,
                               const int* __restrict__ corr,
                               const unsigned short* __restrict__ Tq, const unsigned short* __restrict__ Tc,
                               const unsigned short* __restrict__ Tqd, const unsigned short* __restrict__ Tcd,
                               const float* __restrict__ bx, unsigned short* __restrict__ xg,
                               float* __restrict__ SSg, float* __restrict__ corrf) {
  const int r = blockIdx.x * 16 + (threadIdx.x >> 4);   // r = s*1024 + b
  const int c8 = (threadIdx.x & 15) * 8;
  const int s = r >> 10, b = r & 1023;
  const int q = qs[b * S_LEN + s], c = cs[b * S_LEN + s];
  const int qd = qds[b * S_LEN + s], cd = cds[b * S_LEN + s];
  union U8 { uint4 v; unsigned short s[8]; };
  U8 vq, vc, vd, ve, o;
  vq.v = *(const uint4*)(Tq + (size_t)q * DIM + c8);
  vc.v = *(const uint4*)(Tc + (size_t)c * DIM + c8);
  vd.v = *(const uint4*)(Tqd + (size_t)qd * DIM + c8);
  ve.v = *(const uint4*)(Tcd + (size_t)cd * DIM + c8);
  const float4 bx0 = *(const float4*)(bx + c8);
  const float4 bx1 = *(const float4*)(bx + c8 + 4);
  float bb[8] = {bx0.x, bx0.y, bx0.z, bx0.w, bx1.x, bx1.y, bx1.z, bx1.w};
  float part = 0.f;
#pragma unroll
  for (int j = 0; j < 8; ++j) {
    const float sv = b2f(vq.s[j]) + b2f(vc.s[j]) + b2f(vd.s[j]) + b2f(ve.s[j]) + bb[j];
    o.s[j] = f2b(sv);
    const float xr = b2f(o.s[j]);
    part = fmaf(xr, xr, part);
  }
  *(uint4*)(xg + (size_t)r * DIM + c8) = o.v;
#pragma unroll
  for (int off = 1; off <= 8; off <<= 1) part += __shfl_xor(part, off, 64);
  if ((threadIdx.x & 15) == 0) {
    SSg[r] = part;
    corrf[r] = (float)corr[b * S_LEN + s];
  }
}

// ---------------- P3: GG[r][:] = x[r]@Wkh.T + Tkc[ci] + Tkqd[qi] + Tkcd[di]
// (incl bk via Tkc). 64 rows/block, fused table-sum staged in LDS.
__global__ void gemm_xg_kernel(const unsigned short* __restrict__ xg,
                               const float* __restrict__ Wk,
                               const int* __restrict__ corr, const int* __restrict__ qds,
                               const int* __restrict__ cds,
                               const float* __restrict__ Tkc,
                               const unsigned short* __restrict__ Tkqd,
                               const unsigned short* __restrict__ Tkcd,
                               unsigned short* __restrict__ GG) {
  const int tid = threadIdx.x;
  const int r0 = blockIdx.x * 64;   // r = t*1024 + b, t <= 198
  __shared__ __align__(16) unsigned short TS[64][136];
  {
    const int row = tid >> 2, cb = (tid & 3) * 32;
    const int r = r0 + row, t = r >> 10, b = r & 1023;
    const int ci = corr[b * S_LEN + t], qi = qds[b * S_LEN + t], di = cds[b * S_LEN + t];
    union U8 { uint4 v; unsigned short s[8]; };
#pragma unroll
    for (int cc = 0; cc < 4; ++cc) {
      const int c8 = cb + cc * 8;
      U8 vq, vc, o;
      vq.v = *(const uint4*)(Tkqd + (size_t)qi * DIM + c8);
      vc.v = *(const uint4*)(Tkcd + (size_t)di * DIM + c8);
      const float4 k0 = *(const float4*)(Tkc + (size_t)ci * DIM + c8);
      const float4 k1 = *(const float4*)(Tkc + (size_t)ci * DIM + c8 + 4);
      float kk[8] = {k0.x, k0.y, k0.z, k0.w, k1.x, k1.y, k1.z, k1.w};
#pragma unroll
      for (int j = 0; j < 8; ++j) o.s[j] = f2b(kk[j] + b2f(vq.s[j]) + b2f(vc.s[j]));
      *(uint4*)&TS[row][c8] = o.v;
    }
  }
  __syncthreads();
  const int w = tid >> 6, L = tid & 63, q = L >> 4, m = L & 15;
  short8 wk[2][4];
#pragma unroll
  for (int T = 0; T < 2; ++T) {
    const int n = 32 * w + 16 * T + m;
#pragma unroll
    for (int kb = 0; kb < 4; ++kb) {
      const float* src = Wk + (size_t)n * 512 + kb * 32 + q * 8;
      const float4 v0 = *(const float4*)src;
      const float4 v1 = *(const float4*)(src + 4);
      short8 f;
      f[0] = (short)f2b(v0.x); f[1] = (short)f2b(v0.y);
      f[2] = (short)f2b(v0.z); f[3] = (short)f2b(v0.w);
      f[4] = (short)f2b(v1.x); f[5] = (short)f2b(v1.y);
      f[6] = (short)f2b(v1.z); f[7] = (short)f2b(v1.w);
      wk[T][kb] = f;
    }
  }
  const f32x4 vzero = {0.f, 0.f, 0.f, 0.f};
#pragma unroll
  for (int mt = 0; mt < 4; ++mt) {
    short8 af[4];
#pragma unroll
    for (int kb = 0; kb < 4; ++kb)
      af[kb] = *(const short8*)(xg + (size_t)(r0 + mt * 16 + m) * DIM + kb * 32 + q * 8);
    f32x4 acc[2] = {vzero, vzero};
#pragma unroll
    for (int kb = 0; kb < 4; ++kb) {
#pragma unroll
      for (int T = 0; T < 2; ++T)
        acc[T] = __builtin_amdgcn_mfma_f32_16x16x32_bf16(af[kb], wk[T][kb], acc[T], 0, 0, 0);
    }
#pragma unroll
    for (int T = 0; T < 2; ++T) {
      const int col = 32 * w + 16 * T + m;
#pragma unroll
      for (int i = 0; i < 4; ++i) {
        const int row64 = mt * 16 + q * 4 + i;
        GG[(size_t)(r0 + row64) * DIM + col] = f2b(acc[T][i] + b2f(TS[row64][col]));
      }
    }
  }
}

// ---------------- P4: the recurrence. 64 blocks x 512 thr (8 waves x 16 cols).
__global__ __launch_bounds__(512, 2) void scan_kernel(
    const unsigned short* __restrict__ xg,    // [S][B][D] bf16
    const unsigned short* __restrict__ gg,    // [S-1][B][D] bf16
    const float* __restrict__ SSg,            // [S][B] fp32
    const float* __restrict__ corrf,          // [S][B] fp32 (0.0/1.0)
    const float* __restrict__ h0,
    const float* __restrict__ Ws1, const float* __restrict__ bs1,
    const float* __restrict__ Ws2, const float* __restrict__ bs2,
    const float* __restrict__ Wp1, const float* __restrict__ Wp2,
    const float* __restrict__ Wk,
    const float* __restrict__ gTp1c, const float* __restrict__ gTp2c,
    float* __restrict__ outp) {
  __shared__ __align__(16) unsigned short Sbuf[16][136];
  __shared__ __align__(16) unsigned short Pbuf[16][136];

  const int tid = threadIdx.x;
  const int w = tid >> 6, L = tid & 63, q = L >> 4, m = L & 15;
  const int col16 = 16 * w + m;
  const int rbase = blockIdx.x << 4;
  const size_t SB = (size_t)NBATCH * DIM;

  short8 wf[5][4];
  {
    const float* Wptr[5] = {Ws1, Ws2, Wp1, Wp2, Wk};
    const int ldw[5] = {128, 128, 256, 256, 512};
#pragma unroll
    for (int M = 0; M < 5; ++M) {
#pragma unroll
      for (int kb = 0; kb < 4; ++kb) {
        const float* src = Wptr[M] + (size_t)col16 * ldw[M] + kb * 32 + q * 8;
        const float4 v0 = *(const float4*)src;
        const float4 v1 = *(const float4*)(src + 4);
        short8 f;
        f[0] = (short)f2b(v0.x); f[1] = (short)f2b(v0.y);
        f[2] = (short)f2b(v0.z); f[3] = (short)f2b(v0.w);
        f[4] = (short)f2b(v1.x); f[5] = (short)f2b(v1.y);
        f[6] = (short)f2b(v1.z); f[7] = (short)f2b(v1.w);
        wf[M][kb] = f;
      }
    }
  }
  const float bs1v = bs1[col16], bs2v = bs2[col16];
  const float tp1v0 = gTp1c[col16], dtp1 = gTp1c[DIM + col16] - tp1v0;
  const float tp2v0 = gTp2c[col16], dtp2 = gTp2c[DIM + col16] - tp2v0;

  float h[4];
#pragma unroll
  for (int i = 0; i < 4; ++i) {
    const int b = rbase + q * 4 + i;
    const float hv = h0[(size_t)b * DIM + col16];
    h[i] = hv;
    const float xt = b2f(xg[(size_t)b * DIM + col16]);
    Sbuf[q * 4 + i][col16] = f2b(xt - hv);
  }
  if (tid < 16) outp[(size_t)(rbase + tid) * S_LEN + (S_LEN - 1)] = 0.0f;
  float* poy = outp + (size_t)(rbase + m) * S_LEN;   // wave0 y stores, imm-offset t

  // distance-2 prefetch: register sets A/B + walking pointers (imm offsets)
  unsigned short XPA[4], XPB[4], GPA[4], GPB[4];
  float4 CFA, CFB;
  short8 XFA[4], XFB[4];
  float SSA, SSB;
  const unsigned short* pxA = xg + 3 * SB + (size_t)(rbase + q * 4) * DIM + col16;
  const unsigned short* pxB = pxA + SB;
  const unsigned short* pgA = gg + 2 * SB + (size_t)(rbase + q * 4) * DIM + col16;
  const unsigned short* pgB = pgA + SB;
  const float* pcA = corrf + 2 * NBATCH + rbase + q * 4;
  const float* pcB = pcA + NBATCH;
  const unsigned short* pfA = xg + 2 * SB + (size_t)(rbase + m) * DIM + q * 8;
  const unsigned short* pfB = pfA + SB;
  const float* psA = SSg + 2 * NBATCH + rbase + m;
  const float* psB = psA + NBATCH;
#pragma unroll
  for (int i = 0; i < 4; ++i) {
    XPA[i] = xg[SB + (size_t)(rbase + q * 4 + i) * DIM + col16];      // x[1]
    XPB[i] = xg[2 * SB + (size_t)(rbase + q * 4 + i) * DIM + col16];  // x[2]
    GPA[i] = gg[(size_t)(rbase + q * 4 + i) * DIM + col16];           // gg[0]
    GPB[i] = gg[SB + (size_t)(rbase + q * 4 + i) * DIM + col16];      // gg[1]
  }
  CFA = *(const float4*)(corrf + rbase + q * 4);
  CFB = *(const float4*)(corrf + NBATCH + rbase + q * 4);
#pragma unroll
  for (int kb = 0; kb < 4; ++kb) {
    XFA[kb] = *(const short8*)(xg + (size_t)(rbase + m) * DIM + kb * 32 + q * 8);        // x[0]
    XFB[kb] = *(const short8*)(xg + SB + (size_t)(rbase + m) * DIM + kb * 32 + q * 8);   // x[1]
  }
  SSA = SSg[rbase + m];
  SSB = SSg[NBATCH + rbase + m];

  const f32x4 vzero = {0.f, 0.f, 0.f, 0.f};

#define STEP(TCUR, XP, GP, CF, PX, PG, PC, XF, SSR, PF, PS)                    \
  do {                                                                         \
    const int t_ = (TCUR);                                                     \
    float xnv[4], ggv[4], cfv[4];                                              \
    _Pragma("unroll") for (int i = 0; i < 4; ++i) {                            \
      xnv[i] = b2f(XP[i]); ggv[i] = b2f(GP[i]);                                \
    }                                                                          \
    cfv[0] = CF.x; cfv[1] = CF.y; cfv[2] = CF.z; cfv[3] = CF.w;                \
    short8 xfr[4]; float ssv = SSR;                                            \
    if (w == 0) {                                                              \
      _Pragma("unroll") for (int kb = 0; kb < 4; ++kb) xfr[kb] = XF[kb];       \
    }                                                                          \
    _Pragma("unroll") for (int i = 0; i < 4; ++i) {                            \
      XP[i] = PX[i * DIM]; GP[i] = PG[i * DIM];                                \
    }                                                                          \
    CF = *(const float4*)PC;                                                   \
    PX += 2 * SB; PG += 2 * SB; PC += 2 * NBATCH;                              \
    if (w == 0) {                                                              \
      _Pragma("unroll") for (int kb = 0; kb < 4; ++kb)                         \
        XF[kb] = *(const short8*)(PF + kb * 32);                               \
      SSR = *PS;                                                               \
      PF += 2 * SB; PS += 2 * NBATCH;                                          \
    }                                                                          \
    wg_barrier_lds(); /* Sbuf(t) ready */                                      \
    short8 sf[4];                                                              \
    _Pragma("unroll") for (int kb = 0; kb < 4; ++kb)                           \
        sf[kb] = *(const short8*)&Sbuf[m][kb * 32 + q * 8];                    \
    f32x4 a1 = vzero, a2 = vzero, c1 = vzero;                                  \
    _Pragma("unroll") for (int kb = 0; kb < 4; ++kb) {                         \
      a1 = __builtin_amdgcn_mfma_f32_16x16x32_bf16(sf[kb], wf[0][kb], a1, 0, 0, 0); \
      a2 = __builtin_amdgcn_mfma_f32_16x16x32_bf16(sf[kb], wf[1][kb], a2, 0, 0, 0); \
      c1 = __builtin_amdgcn_mfma_f32_16x16x32_bf16(sf[kb], wf[4][kb], c1, 0, 0, 0); \
    }                                                                          \
    if (w == 0) {                                                              \
      f32x4 dt = vzero;                                                        \
      _Pragma("unroll") for (int kb = 0; kb < 4; ++kb)                         \
        dt = __builtin_amdgcn_mfma_f32_16x16x32_bf16(sf[kb], xfr[kb], dt, 0, 0, 0); \
      if (t_ > 0 && q == (m >> 2)) {                                           \
        const int ii = m & 3;                                                  \
        const float D = ii == 0 ? dt[0] : ii == 1 ? dt[1] : ii == 2 ? dt[2] : dt[3]; \
        poy[t_ - 1] = fast_sigmoid(ssv - D);                                   \
      }                                                                        \
    }                                                                          \
    _Pragma("unroll") for (int i2 = 0; i2 < 2; ++i2) {                         \
      const float s0 = fast_sigmoid(a1[2 * i2] + bs1v) * fast_tanh(a2[2 * i2] + bs2v); \
      const float s1 = fast_sigmoid(a1[2 * i2 + 1] + bs1v) * fast_tanh(a2[2 * i2 + 1] + bs2v); \
      const unsigned u = pk_bf16(s0, s1);                                      \
      Pbuf[q * 4 + 2 * i2][col16] = (unsigned short)u;                         \
      Pbuf[q * 4 + 2 * i2 + 1][col16] = (unsigned short)(u >> 16);             \
    }                                                                          \
    wg_barrier_lds(); /* Pbuf ready */                                         \
    short8 pf[4];                                                              \
    _Pragma("unroll") for (int kb = 0; kb < 4; ++kb)                           \
        pf[kb] = *(const short8*)&Pbuf[m][kb * 32 + q * 8];                    \
    f32x4 p1 = vzero, p2 = vzero;                                              \
    _Pragma("unroll") for (int kb = 0; kb < 4; ++kb) {                         \
      p1 = __builtin_amdgcn_mfma_f32_16x16x32_bf16(pf[kb], wf[2][kb], p1, 0, 0, 0); \
      p2 = __builtin_amdgcn_mfma_f32_16x16x32_bf16(pf[kb], wf[3][kb], p2, 0, 0, 0); \
    }                                                                          \
    float sn[4];                                                               \
    _Pragma("unroll") for (int i = 0; i < 4; ++i) {                            \
      const float g = fast_sigmoid(ggv[i] - c1[i]);                            \
      const float t1v = fmaf(cfv[i], dtp1, tp1v0);                             \
      const float t2v = fmaf(cfv[i], dtp2, tp2v0);                             \
      const float pka = fast_sigmoid(p1[i] + t1v) * fast_tanh(p2[i] + t2v);    \
      const float hn = pka + g * (h[i] - pka);                                 \
      h[i] = hn;                                                               \
      sn[i] = xnv[i] - hn;                                                     \
    }                                                                          \
    _Pragma("unroll") for (int i2 = 0; i2 < 2; ++i2) {                         \
      const unsigned u = pk_bf16(sn[2 * i2], sn[2 * i2 + 1]);                  \
      Sbuf[q * 4 + 2 * i2][col16] = (unsigned short)u;                         \
      Sbuf[q * 4 + 2 * i2 + 1][col16] = (unsigned short)(u >> 16);             \
    }                                                                          \
  } while (0)

  for (int t2 = 0; t2 < 198; t2 += 2) {
    STEP(t2, XPA, GPA, CFA, pxA, pgA, pcA, XFA, SSA, pfA, psA);
    STEP(t2 + 1, XPB, GPB, CFB, pxB, pgB, pcB, XFB, SSB, pfB, psB);
  }
  STEP(198, XPA, GPA, CFA, pxA, pgA, pcA, XFA, SSA, pfA, psA);
#undef STEP

  // epilogue: y(198) from s(199) in Sbuf, x[199] (= XFB), ss[199] (= SSB)
  wg_barrier_lds();
  if (w == 0) {
    short8 sf[4];
#pragma unroll
    for (int kb = 0; kb < 4; ++kb) sf[kb] = *(const short8*)&Sbuf[m][kb * 32 + q * 8];
    f32x4 dt = vzero;
#pragma unroll
    for (int kb = 0; kb < 4; ++kb)
      dt = __builtin_amdgcn_mfma_f32_16x16x32_bf16(sf[kb], XFB[kb], dt, 0, 0, 0);
    if (q == (m >> 2)) {
      const int ii = m & 3;
      const float D = ii == 0 ? dt[0] : ii == 1 ? dt[1] : ii == 2 ? dt[2] : dt[3];
      poy[S_LEN - 2] = fast_sigmoid(SSB - D);
    }
  }
}

extern "C" void kernel_launch(void* const* d_in, const int* in_sizes, int n_in,
                              void* d_out, int out_size, void* d_ws, size_t ws_size,
                              hipStream_t stream) {
  const int* qs    = (const int*)d_in[0];
  const int* cs    = (const int*)d_in[1];
  const int* qds   = (const int*)d_in[2];
  const int* cds   = (const int*)d_in[3];
  const int* corr  = (const int*)d_in[4];
  const float* Eq    = (const float*)d_in[5];
  const float* Ec    = (const float*)d_in[6];
  const float* Eqd   = (const float*)d_in[7];
  const float* Ecd   = (const float*)d_in[8];
  const float* Ecorr = (const float*)d_in[9];
  const float* Wx  = (const float*)d_in[10];
  const float* bx  = (const float*)d_in[11];
  const float* Ws1 = (const float*)d_in[12];
  const float* bs1 = (const float*)d_in[13];
  const float* Ws2 = (const float*)d_in[14];
  const float* bs2 = (const float*)d_in[15];
  const float* Wp1 = (const float*)d_in[16];
  const float* bp1 = (const float*)d_in[17];
  const float* Wp2 = (const float*)d_in[18];
  const float* bp2 = (const float*)d_in[19];
  const float* Wk  = (const float*)d_in[20];
  const float* bk  = (const float*)d_in[21];
  const float* h0  = (const float*)d_in[22];

  char* ws = (char*)d_ws;
  // layout: X | GG (aliases Tq..Tcd during build) | corrf | SS | small tables.
  // Prefetch overruns (<=2 steps past X/GG/corrf/SS ends) land in the next
  // region -- harmless garbage reads inside d_ws, never consumed.
  const size_t xbytes = (size_t)S_LEN * NBATCH * DIM * 2;
  const size_t A = (xbytes + 255) & ~(size_t)255;
  const size_t ggbytes = (size_t)(S_LEN - 1) * NBATCH * DIM * 2;
  unsigned short* X  = (unsigned short*)ws;
  unsigned short* GG = (unsigned short*)(ws + A);
  unsigned short* Tq  = GG;  // alias (dead after build_x)
  unsigned short* Tc  = (unsigned short*)(ws + A + (size_t)50000 * DIM * 2);
  unsigned short* Tqd = (unsigned short*)(ws + A + (size_t)51000 * DIM * 2);
  unsigned short* Tcd = (unsigned short*)(ws + A + (size_t)51101 * DIM * 2);
  size_t off = A + ((ggbytes + 255) & ~(size_t)255);
  auto alloc = [&](size_t bytes) {
    void* p = ws + off;
    off = (off + bytes + 255) & ~(size_t)255;
    return p;
  };
  float* corrf = (float*)alloc((size_t)S_LEN * NBATCH * 4);
  float* SS    = (float*)alloc((size_t)S_LEN * NBATCH * 4);
  unsigned short* Tkqd = (unsigned short*)alloc((size_t)101 * DIM * 2);
  unsigned short* Tkcd = (unsigned short*)alloc((size_t)101 * DIM * 2);
  float* Tkc  = (float*)alloc((size_t)2 * DIM * 4);
  float* Tp1c = (float*)alloc((size_t)2 * DIM * 4);
  float* Tp2c = (float*)alloc((size_t)2 * DIM * 4);

  proj_all_kernel<<<904, 256, 0, stream>>>(Eq, Ec, Eqd, Ecd, Ecorr, Wx,
                                           Wp1, bp1, Wp2, bp2, Wk, bk,
                                           Tq, Tc, Tqd, Tcd, Tkqd, Tkcd, Tkc, Tp1c, Tp2c);
  build_x_kernel<<<(S_LEN * NBATCH) / 16, 256, 0, stream>>>(qs, cs, qds, cds, corr,
                                                            Tq, Tc, Tqd, Tcd, bx, X, SS, corrf);
  // Tq..Tcd dead now -> GG overwrites them
  gemm_xg_kernel<<<((S_LEN - 1) * NBATCH) / 64, 256, 0, stream>>>(X, Wk, corr, qds, cds,
                                                                  Tkc, Tkqd, Tkcd, GG);
  scan_kernel<<<64, 512, 0, stream>>>(X, GG, SS, corrf, h0, Ws1, bs1, Ws2, bs2,
                                      Wp1, Wp2, Wk, Tp1c, Tp2c, (float*)d_out);
}